// Round 3
// baseline (67.016 us; speedup 1.0000x reference)
//
#include <hip/hip_runtime.h>

// LUT layer: out[b,o] = sum_d weights[d, idx[b,d], o]
// idx[b,d] = packed sign bits of x[b, anchors[d, 0..8]]
// B=2048, N_IN=1024, D=512, A=8, C=256, O=256
//
// Strategy: detector-partition across XCDs, high-TLP gather.
//   K1: idx[b][d] (uint8, 1 MB in ws)
//   K2: 1024 blocks = (128 batch-chunks x 8 det-groups); group = bid&7 -> XCD
//       affinity. Each XCD streams only its 16 MB of weight slabs; the 1 GB
//       gather reuse is served by per-XCD L2. 4 blocks/CU for latency hiding.
//   K3: reduce 8 partials -> out.

#define B_TOT   2048
#define N_IN    1024
#define N_DET   512
#define N_ANCH  8
#define N_OUT   256

#define DET_G   8              // detector groups (== XCDs)
#define DPG     (N_DET/DET_G)  // 64 detectors per group
#define BT2     16             // batches per block in gather kernel

#define IDX_BYTES   ((size_t)B_TOT * N_DET)                         // 1 MB
#define PART_BYTES  ((size_t)DET_G * B_TOT * N_OUT * sizeof(float)) // 16 MB

// ---------------- K1: compute LUT indices ----------------
__global__ __launch_bounds__(256) void lut_idx_kernel(
    const float* __restrict__ x,
    const int*   __restrict__ anchors,
    unsigned char* __restrict__ idx_out)
{
    __shared__ unsigned char bits[N_IN];
    const int b = blockIdx.x;
    const int t = threadIdx.x;

    const float4* xg = reinterpret_cast<const float4*>(x + (size_t)b * N_IN);
    float4 v = xg[t];
    bits[t * 4 + 0] = v.x > 0.0f;
    bits[t * 4 + 1] = v.y > 0.0f;
    bits[t * 4 + 2] = v.z > 0.0f;
    bits[t * 4 + 3] = v.w > 0.0f;
    __syncthreads();

    #pragma unroll
    for (int k = 0; k < N_DET / 256; ++k) {
        int d = t + k * 256;
        const int4* a4 = reinterpret_cast<const int4*>(anchors + d * N_ANCH);
        int4 a0 = a4[0];
        int4 a1 = a4[1];
        unsigned idx = 0;
        idx |= (unsigned)bits[a0.x];
        idx |= (unsigned)bits[a0.y] << 1;
        idx |= (unsigned)bits[a0.z] << 2;
        idx |= (unsigned)bits[a0.w] << 3;
        idx |= (unsigned)bits[a1.x] << 4;
        idx |= (unsigned)bits[a1.y] << 5;
        idx |= (unsigned)bits[a1.z] << 6;
        idx |= (unsigned)bits[a1.w] << 7;
        idx_out[(size_t)b * N_DET + d] = (unsigned char)idx;
    }
}

// ---------------- K2: gather-accumulate per detector group ----------------
__global__ __launch_bounds__(256, 4) void lut_gather_kernel(
    const unsigned char* __restrict__ idx,
    const float* __restrict__ weights,
    float* __restrict__ partial)
{
    const int bid = blockIdx.x;
    const int g   = bid & (DET_G - 1);   // det group -> XCD (round-robin)
    const int bc  = bid >> 3;            // batch chunk
    const int b0  = bc * BT2;
    const int d0  = g * DPG;

    __shared__ unsigned char idx_s[DPG][BT2];  // transposed [d][b], 1 KB

    const int t = threadIdx.x;
    // stage idx block: 64 threads each load 16 detector-bytes of one batch row
    if (t < 64) {
        int r  = t >> 2;      // batch 0..15
        int cc = t & 3;       // 16-detector chunk
        uint4 v = *reinterpret_cast<const uint4*>(
            idx + (size_t)(b0 + r) * N_DET + d0 + cc * 16);
        unsigned char* bs = (unsigned char*)&v;
        #pragma unroll
        for (int i = 0; i < 16; ++i) idx_s[cc * 16 + i][r] = bs[i];
    }
    __syncthreads();

    const int wave = t >> 6;
    const int lane = t & 63;

    float4 acc[4];
    #pragma unroll
    for (int j = 0; j < 4; ++j) acc[j] = make_float4(0.f, 0.f, 0.f, 0.f);

    const float* Wg = weights + (size_t)d0 * 256 * 256;  // group base

    #pragma unroll 2
    for (int d = 0; d < DPG; ++d) {
        // 4 channel bytes for this wave's 4 batches; wave-uniform -> scalar
        unsigned v = *reinterpret_cast<const unsigned*>(&idx_s[d][wave * 4]);
        v = __builtin_amdgcn_readfirstlane(v);
        const float4* Wd = reinterpret_cast<const float4*>(Wg + (size_t)d * 65536);
        #pragma unroll
        for (int j = 0; j < 4; ++j) {
            unsigned c = (v >> (8 * j)) & 0xFF;
            float4 w = Wd[(size_t)c * 64 + lane];   // scalar base + lane offset
            acc[j].x += w.x; acc[j].y += w.y; acc[j].z += w.z; acc[j].w += w.w;
        }
    }

    float4* P4 = reinterpret_cast<float4*>(partial);
    #pragma unroll
    for (int j = 0; j < 4; ++j) {
        size_t b = (size_t)b0 + wave * 4 + j;
        P4[((size_t)g * B_TOT + b) * 64 + lane] = acc[j];
    }
}

// ---------------- K3: reduce partials ----------------
__global__ __launch_bounds__(256) void lut_reduce_kernel(
    const float* __restrict__ partial,
    float* __restrict__ out)
{
    const size_t i = (size_t)blockIdx.x * 256 + threadIdx.x; // over 2048*64 f4
    const float4* P4 = reinterpret_cast<const float4*>(partial);
    float4 s = make_float4(0.f, 0.f, 0.f, 0.f);
    #pragma unroll
    for (int g = 0; g < DET_G; ++g) {
        float4 v = P4[(size_t)g * (B_TOT * 64) + i];
        s.x += v.x; s.y += v.y; s.z += v.z; s.w += v.w;
    }
    reinterpret_cast<float4*>(out)[i] = s;
}

// ---------------- fallback: monolithic kernel (small ws) ----------------
#define BT 4
__global__ __launch_bounds__(256) void lut_fused_kernel(
    const float* __restrict__ x,
    const int*   __restrict__ anchors,
    const float* __restrict__ weights,
    float*       __restrict__ out)
{
    __shared__ float x_s[BT][N_IN];
    __shared__ int   idx_s[BT][N_DET];
    const int tid = threadIdx.x;
    const int b0  = blockIdx.x * BT;
    {
        const float4* xg = reinterpret_cast<const float4*>(x + (size_t)b0 * N_IN);
        float4*       xs = reinterpret_cast<float4*>(&x_s[0][0]);
        #pragma unroll
        for (int k = 0; k < BT; ++k) xs[tid + k * 256] = xg[tid + k * 256];
    }
    __syncthreads();
    #pragma unroll
    for (int k = 0; k < (BT * N_DET) / 256; ++k) {
        int p  = tid + k * 256;
        int d  = p & (N_DET - 1);
        int bt = p >> 9;
        const int4* a4 = reinterpret_cast<const int4*>(anchors + d * N_ANCH);
        int4 a0 = a4[0];
        int4 a1 = a4[1];
        int idx = 0;
        idx |= (x_s[bt][a0.x] > 0.0f) ? 1   : 0;
        idx |= (x_s[bt][a0.y] > 0.0f) ? 2   : 0;
        idx |= (x_s[bt][a0.z] > 0.0f) ? 4   : 0;
        idx |= (x_s[bt][a0.w] > 0.0f) ? 8   : 0;
        idx |= (x_s[bt][a1.x] > 0.0f) ? 16  : 0;
        idx |= (x_s[bt][a1.y] > 0.0f) ? 32  : 0;
        idx |= (x_s[bt][a1.z] > 0.0f) ? 64  : 0;
        idx |= (x_s[bt][a1.w] > 0.0f) ? 128 : 0;
        idx_s[bt][d] = idx;
    }
    __syncthreads();
    const int wave = tid >> 6;
    const int lane = tid & 63;
    float4 acc = make_float4(0.0f, 0.0f, 0.0f, 0.0f);
    const float4* W4 = reinterpret_cast<const float4*>(weights);
    #pragma unroll 8
    for (int d = 0; d < N_DET; ++d) {
        int idx = idx_s[wave][d];
        size_t row = (size_t)(d << 8) + (size_t)idx;
        float4 w = W4[row * 64 + lane];
        acc.x += w.x; acc.y += w.y; acc.z += w.z; acc.w += w.w;
    }
    float4* out4 = reinterpret_cast<float4*>(out + (size_t)(b0 + wave) * N_OUT);
    out4[lane] = acc;
}

extern "C" void kernel_launch(void* const* d_in, const int* in_sizes, int n_in,
                              void* d_out, int out_size, void* d_ws, size_t ws_size,
                              hipStream_t stream) {
    const float* x       = (const float*)d_in[0];
    const int*   anchors = (const int*)  d_in[1];
    const float* weights = (const float*)d_in[2];
    float*       out     = (float*)d_out;

    if (ws_size >= IDX_BYTES + PART_BYTES) {
        unsigned char* idx_ws  = (unsigned char*)d_ws;
        float*         part_ws = (float*)((char*)d_ws + IDX_BYTES);

        lut_idx_kernel<<<dim3(B_TOT), dim3(256), 0, stream>>>(x, anchors, idx_ws);
        lut_gather_kernel<<<dim3((B_TOT / BT2) * DET_G), dim3(256), 0, stream>>>(
            idx_ws, weights, part_ws);
        lut_reduce_kernel<<<dim3(B_TOT * N_OUT / 4 / 256), dim3(256), 0, stream>>>(
            part_ws, out);
    } else {
        lut_fused_kernel<<<dim3(B_TOT / BT), dim3(256), 0, stream>>>(
            x, anchors, weights, out);
    }
}

// Round 5
// 61.865 us; speedup vs baseline: 1.0833x; 1.0833x over previous
//
#include <hip/hip_runtime.h>

// LUT layer: out[b,o] = sum_d weights[d, idx[b,d], o]
// idx[b,d] = packed sign bits of x[b, anchors[d, 0..8]]
// B=2048, N_IN=1024, D=512, A=8, C=256, O=256
//
// Strategy: detector-partition across XCDs (8 groups of 64), r2 shape:
//   512 gather blocks (2/CU, minimal detector-phase skew), 32 batches/block.
//   Scalar (readfirstlane) channel words -> scalar-base loads; prefetched
//   channel words + unroll 2 keep ~16 loads in flight per wave.
//   Partials stored nontemporally (don't evict gather slabs from L2).

typedef float f32x4 __attribute__((ext_vector_type(4)));

#define B_TOT   2048
#define N_IN    1024
#define N_DET   512
#define N_ANCH  8
#define N_OUT   256

#define DET_G   8              // detector groups (== XCDs)
#define DPG     (N_DET/DET_G)  // 64 detectors per group
#define BT2     32             // batches per block in gather kernel

#define IDX_BYTES   ((size_t)B_TOT * N_DET)                         // 1 MB
#define PART_BYTES  ((size_t)DET_G * B_TOT * N_OUT * sizeof(float)) // 16 MB

// ---------------- K1: compute LUT indices ----------------
__global__ __launch_bounds__(256) void lut_idx_kernel(
    const float* __restrict__ x,
    const int*   __restrict__ anchors,
    unsigned char* __restrict__ idx_out)
{
    __shared__ unsigned char bits[N_IN];
    const int b = blockIdx.x;
    const int t = threadIdx.x;

    const float4* xg = reinterpret_cast<const float4*>(x + (size_t)b * N_IN);
    float4 v = xg[t];
    bits[t * 4 + 0] = v.x > 0.0f;
    bits[t * 4 + 1] = v.y > 0.0f;
    bits[t * 4 + 2] = v.z > 0.0f;
    bits[t * 4 + 3] = v.w > 0.0f;
    __syncthreads();

    #pragma unroll
    for (int k = 0; k < N_DET / 256; ++k) {
        int d = t + k * 256;
        const int4* a4 = reinterpret_cast<const int4*>(anchors + d * N_ANCH);
        int4 a0 = a4[0];
        int4 a1 = a4[1];
        unsigned idx = 0;
        idx |= (unsigned)bits[a0.x];
        idx |= (unsigned)bits[a0.y] << 1;
        idx |= (unsigned)bits[a0.z] << 2;
        idx |= (unsigned)bits[a0.w] << 3;
        idx |= (unsigned)bits[a1.x] << 4;
        idx |= (unsigned)bits[a1.y] << 5;
        idx |= (unsigned)bits[a1.z] << 6;
        idx |= (unsigned)bits[a1.w] << 7;
        idx_out[(size_t)b * N_DET + d] = (unsigned char)idx;
    }
}

// ---------------- K2: gather-accumulate per detector group ----------------
__global__ __launch_bounds__(256, 2) void lut_gather_kernel(
    const unsigned char* __restrict__ idx,
    const float* __restrict__ weights,
    float* __restrict__ partial)
{
    const int bid = blockIdx.x;
    const int g   = bid & (DET_G - 1);   // det group -> XCD (round-robin)
    const int bc  = bid >> 3;            // batch chunk
    const int b0  = bc * BT2;
    const int d0  = g * DPG;

    __shared__ unsigned char idx_s[DPG][BT2];  // transposed [d][b], 2 KB

    const int t = threadIdx.x;
    // stage idx block: thread t loads 8 det-bytes for batch r=t>>3, dets cc=t&7
    {
        int r  = t >> 3;
        int cc = t & 7;
        uint2 v = *reinterpret_cast<const uint2*>(
            idx + (size_t)(b0 + r) * N_DET + d0 + cc * 8);
        unsigned char* bs = (unsigned char*)&v;
        #pragma unroll
        for (int i = 0; i < 8; ++i) idx_s[cc * 8 + i][r] = bs[i];
    }
    __syncthreads();

    const int wave = t >> 6;
    const int lane = t & 63;

    f32x4 acc[8];
    #pragma unroll
    for (int j = 0; j < 8; ++j) acc[j] = (f32x4){0.f, 0.f, 0.f, 0.f};

    // group base + lane offset folded in; rows are 64 float4 long
    const f32x4* Wg = reinterpret_cast<const f32x4*>(weights)
                    + (size_t)d0 * 256 * 64 + lane;

    // prefetch channel words for d=0 (wave-uniform -> scalar)
    unsigned w0 = __builtin_amdgcn_readfirstlane(
        *reinterpret_cast<const unsigned*>(&idx_s[0][wave * 8]));
    unsigned w1 = __builtin_amdgcn_readfirstlane(
        *reinterpret_cast<const unsigned*>(&idx_s[0][wave * 8 + 4]));

    #pragma unroll 2
    for (int d = 0; d < DPG; ++d) {
        const unsigned lo = w0, hi = w1;
        if (d + 1 < DPG) {
            w0 = __builtin_amdgcn_readfirstlane(
                *reinterpret_cast<const unsigned*>(&idx_s[d + 1][wave * 8]));
            w1 = __builtin_amdgcn_readfirstlane(
                *reinterpret_cast<const unsigned*>(&idx_s[d + 1][wave * 8 + 4]));
        }
        const f32x4* Wd = Wg + (size_t)d * 256 * 64;
        f32x4 r[8];
        #pragma unroll
        for (int j = 0; j < 4; ++j)
            r[j] = Wd[(size_t)((lo >> (8 * j)) & 0xFF) * 64];
        #pragma unroll
        for (int j = 0; j < 4; ++j)
            r[4 + j] = Wd[(size_t)((hi >> (8 * j)) & 0xFF) * 64];
        #pragma unroll
        for (int j = 0; j < 8; ++j)
            acc[j] += r[j];
    }

    f32x4* P4 = reinterpret_cast<f32x4*>(partial);
    #pragma unroll
    for (int j = 0; j < 8; ++j) {
        size_t b = (size_t)b0 + wave * 8 + j;
        __builtin_nontemporal_store(acc[j],
            &P4[((size_t)g * B_TOT + b) * 64 + lane]);
    }
}

// ---------------- K3: reduce partials ----------------
__global__ __launch_bounds__(256) void lut_reduce_kernel(
    const float* __restrict__ partial,
    float* __restrict__ out)
{
    const size_t i = (size_t)blockIdx.x * 256 + threadIdx.x; // over 2048*64 f4
    const f32x4* P4 = reinterpret_cast<const f32x4*>(partial);
    f32x4 s = (f32x4){0.f, 0.f, 0.f, 0.f};
    #pragma unroll
    for (int g = 0; g < DET_G; ++g) {
        f32x4 v = __builtin_nontemporal_load(&P4[(size_t)g * (B_TOT * 64) + i]);
        s += v;
    }
    reinterpret_cast<f32x4*>(out)[i] = s;
}

// ---------------- fallback: monolithic kernel (small ws) ----------------
#define BT 4
__global__ __launch_bounds__(256) void lut_fused_kernel(
    const float* __restrict__ x,
    const int*   __restrict__ anchors,
    const float* __restrict__ weights,
    float*       __restrict__ out)
{
    __shared__ float x_s[BT][N_IN];
    __shared__ int   idx_s[BT][N_DET];
    const int tid = threadIdx.x;
    const int b0  = blockIdx.x * BT;
    {
        const float4* xg = reinterpret_cast<const float4*>(x + (size_t)b0 * N_IN);
        float4*       xs = reinterpret_cast<float4*>(&x_s[0][0]);
        #pragma unroll
        for (int k = 0; k < BT; ++k) xs[tid + k * 256] = xg[tid + k * 256];
    }
    __syncthreads();
    #pragma unroll
    for (int k = 0; k < (BT * N_DET) / 256; ++k) {
        int p  = tid + k * 256;
        int d  = p & (N_DET - 1);
        int bt = p >> 9;
        const int4* a4 = reinterpret_cast<const int4*>(anchors + d * N_ANCH);
        int4 a0 = a4[0];
        int4 a1 = a4[1];
        int idx = 0;
        idx |= (x_s[bt][a0.x] > 0.0f) ? 1   : 0;
        idx |= (x_s[bt][a0.y] > 0.0f) ? 2   : 0;
        idx |= (x_s[bt][a0.z] > 0.0f) ? 4   : 0;
        idx |= (x_s[bt][a0.w] > 0.0f) ? 8   : 0;
        idx |= (x_s[bt][a1.x] > 0.0f) ? 16  : 0;
        idx |= (x_s[bt][a1.y] > 0.0f) ? 32  : 0;
        idx |= (x_s[bt][a1.z] > 0.0f) ? 64  : 0;
        idx |= (x_s[bt][a1.w] > 0.0f) ? 128 : 0;
        idx_s[bt][d] = idx;
    }
    __syncthreads();
    const int wave = tid >> 6;
    const int lane = tid & 63;
    float4 acc = make_float4(0.0f, 0.0f, 0.0f, 0.0f);
    const float4* W4 = reinterpret_cast<const float4*>(weights);
    #pragma unroll 8
    for (int d = 0; d < N_DET; ++d) {
        int idx = idx_s[wave][d];
        size_t row = (size_t)(d << 8) + (size_t)idx;
        float4 w = W4[row * 64 + lane];
        acc.x += w.x; acc.y += w.y; acc.z += w.z; acc.w += w.w;
    }
    float4* out4 = reinterpret_cast<float4*>(out + (size_t)(b0 + wave) * N_OUT);
    out4[lane] = acc;
}

extern "C" void kernel_launch(void* const* d_in, const int* in_sizes, int n_in,
                              void* d_out, int out_size, void* d_ws, size_t ws_size,
                              hipStream_t stream) {
    const float* x       = (const float*)d_in[0];
    const int*   anchors = (const int*)  d_in[1];
    const float* weights = (const float*)d_in[2];
    float*       out     = (float*)d_out;

    if (ws_size >= IDX_BYTES + PART_BYTES) {
        unsigned char* idx_ws  = (unsigned char*)d_ws;
        float*         part_ws = (float*)((char*)d_ws + IDX_BYTES);

        lut_idx_kernel<<<dim3(B_TOT), dim3(256), 0, stream>>>(x, anchors, idx_ws);
        lut_gather_kernel<<<dim3((B_TOT / BT2) * DET_G), dim3(256), 0, stream>>>(
            idx_ws, weights, part_ws);
        lut_reduce_kernel<<<dim3(B_TOT * N_OUT / 4 / 256), dim3(256), 0, stream>>>(
            part_ws, out);
    } else {
        lut_fused_kernel<<<dim3(B_TOT / BT), dim3(256), 0, stream>>>(
            x, anchors, weights, out);
    }
}